// Round 1
// baseline (328.636 us; speedup 1.0000x reference)
//
#include <hip/hip_runtime.h>

#define NTOK 32768      // 8*4096 tokens
#define HDIM 1024
#define NEXP 64
#define TK   8
#define NB   8
#define SEQ  4096

#define TB   64         // tokens per block
#define KC   64         // k chunk
#define PA   68         // sA pitch (floats) — rows land on distinct banks for consecutive-row reads
#define PW   68         // sW (transposed) pitch (floats)
#define PLD  65         // dlog pitch (doubles)
#define NTHR 256

// Fused: logits GEMM (fp64 accum) + softmax + top-8 + renorm + per-block stats.
__global__ __launch_bounds__(NTHR, 2) void moe_main(
    const float* __restrict__ hidden,   // [NTOK][HDIM]
    const float* __restrict__ weight,   // [NEXP][HDIM]
    float* __restrict__ out,            // idx[NTOK*TK] | w[NTOK*TK] | aux | counts[64]
    float* __restrict__ ws)             // C[8][64] | Sm[8][64]
{
    __shared__ __align__(16) float smem[TB * PA + KC * PW]; // 34816 B
    float*  sA   = smem;                 // [TB][PA]
    float*  sW   = smem + TB * PA;       // [KC][PW] transposed: [k][e]
    double* dlog = (double*)smem;        // phase-2 alias: [16][PLD] = 8320 B
    __shared__ float smSum[NEXP];
    __shared__ int   hist[NEXP];

    const int tid = threadIdx.x;
    const int tg  = tid >> 4;            // 0..15 token group
    const int eg  = tid & 15;            // 0..15 expert group (experts 4*eg..4*eg+3)
    const int t0  = blockIdx.x * TB;

    if (tid < NEXP) { smSum[tid] = 0.f; hist[tid] = 0; }

    double acc[4][4];
#pragma unroll
    for (int i = 0; i < 4; ++i)
#pragma unroll
        for (int j = 0; j < 4; ++j) acc[i][j] = 0.0;

    for (int kc = 0; kc < HDIM; kc += KC) {
        __syncthreads();
        // stage A: 64 rows x 64 floats = 1024 float4, 4 per thread, coalesced
#pragma unroll
        for (int it = 0; it < 4; ++it) {
            int idx = it * NTHR + tid;
            int r = idx >> 4, c4 = idx & 15;
            float4 v = *(const float4*)(hidden + (size_t)(t0 + r) * HDIM + kc + c4 * 4);
            *(float4*)(sA + r * PA + c4 * 4) = v;
        }
        // stage W transposed: sW[k][e]
#pragma unroll
        for (int it = 0; it < 4; ++it) {
            int idx = it * NTHR + tid;
            int e = idx >> 4, c4 = idx & 15;
            float4 v = *(const float4*)(weight + (size_t)e * HDIM + kc + c4 * 4);
            sW[(c4 * 4 + 0) * PW + e] = v.x;
            sW[(c4 * 4 + 1) * PW + e] = v.y;
            sW[(c4 * 4 + 2) * PW + e] = v.z;
            sW[(c4 * 4 + 3) * PW + e] = v.w;
        }
        __syncthreads();
#pragma unroll 4
        for (int k4 = 0; k4 < KC / 4; ++k4) {
            float a4v[4][4], w4v[4][4];
#pragma unroll
            for (int i = 0; i < 4; ++i) {
                float4 t = *(const float4*)(sA + (tg + 16 * i) * PA + k4 * 4);
                a4v[i][0] = t.x; a4v[i][1] = t.y; a4v[i][2] = t.z; a4v[i][3] = t.w;
            }
#pragma unroll
            for (int m = 0; m < 4; ++m) {
                float4 t = *(const float4*)(sW + (k4 * 4 + m) * PW + 4 * eg);
                w4v[m][0] = t.x; w4v[m][1] = t.y; w4v[m][2] = t.z; w4v[m][3] = t.w;
            }
#pragma unroll
            for (int m = 0; m < 4; ++m) {
                double w0 = (double)w4v[m][0], w1 = (double)w4v[m][1];
                double w2 = (double)w4v[m][2], w3 = (double)w4v[m][3];
#pragma unroll
                for (int i = 0; i < 4; ++i) {
                    double ad = (double)a4v[i][m];
                    acc[i][0] += ad * w0; acc[i][1] += ad * w1;
                    acc[i][2] += ad * w2; acc[i][3] += ad * w3;
                }
            }
        }
    }

    // ---- phase 2: per-token softmax + top-8, processed in 4 quarters of 16 tokens ----
    const int wave = tid >> 6;
    const int lane = tid & 63;   // lane == expert id
    float regSm = 0.f;

    for (int i = 0; i < 4; ++i) {
        __syncthreads();   // quarter i: safe to overwrite sA alias
#pragma unroll
        for (int j = 0; j < 4; ++j)
            dlog[tg * PLD + 4 * eg + j] = acc[i][j];
        __syncthreads();
#pragma unroll
        for (int qq = 0; qq < 4; ++qq) {
            int q = wave * 4 + qq;              // local token in quarter
            double xd = dlog[q * PLD + lane];
            float x = (float)xd;
            float mx = x;
#pragma unroll
            for (int off = 32; off; off >>= 1) mx = fmaxf(mx, __shfl_xor(mx, off));
            float p = __expf(x - mx);
            float s = p;
#pragma unroll
            for (int off = 32; off; off >>= 1) s += __shfl_xor(s, off);
            float score = p / s;
            regSm += score;

            // top-8 on fp64 logits (monotone w/ softmax); tie -> smaller index.
            double vd = xd;
            int selIdx = 0; float selVal = 0.f;
#pragma unroll
            for (int r = 0; r < TK; ++r) {
                unsigned long long u = (unsigned long long)__double_as_longlong(vd);
                unsigned long long mk = (u & 0x8000000000000000ull) ? ~u : (u | 0x8000000000000000ull);
                unsigned long long key = (mk & 0xFFFFFFFFFFFFFFC0ull) | (unsigned long long)(63 - lane);
#pragma unroll
                for (int off = 32; off; off >>= 1) {
                    unsigned long long o = __shfl_xor(key, off);
                    if (o > key) key = o;
                }
                int winner = 63 - (int)(key & 63ull);
                float wsc = __shfl(score, winner);
                if (lane == r) { selIdx = winner; selVal = wsc; }
                if (lane == winner) vd = -__builtin_inf();
            }
            float dv = (lane < TK) ? selVal : 0.f;
#pragma unroll
            for (int off = 32; off; off >>= 1) dv += __shfl_xor(dv, off);
            int t = t0 + 16 * i + q;
            if (lane < TK) {
                out[(size_t)t * TK + lane] = (float)selIdx;                       // indices (as float)
                out[(size_t)NTOK * TK + (size_t)t * TK + lane] = selVal / (dv + 1e-20f);
                atomicAdd(&hist[selIdx], 1);
            }
        }
    }
    atomicAdd(&smSum[lane], regSm);
    __syncthreads();
    if (tid < NEXP) {
        int b = blockIdx.x >> 6;            // 64 blocks per batch
        atomicAdd(&ws[b * NEXP + tid], (float)hist[tid]);
        atomicAdd(&ws[NB * NEXP + b * NEXP + tid], smSum[tid]);
    }
}

__global__ void moe_finalize(const float* __restrict__ ws, float* __restrict__ out)
{
    int e = threadIdx.x;   // 64 threads
    float cnt = 0.f, accv = 0.f;
#pragma unroll
    for (int b = 0; b < NB; ++b) {
        float c  = ws[b * NEXP + e];
        float sm = ws[NB * NEXP + b * NEXP + e];
        cnt += c;
        accv += c * sm;
    }
    out[(size_t)NTOK * TK * 2 + 1 + e] = cnt;   // expert_counts (as float)
#pragma unroll
    for (int off = 32; off; off >>= 1) accv += __shfl_xor(accv, off);
    if (e == 0) {
        // aux = ALPHA * (1/NB) * sum_{b,e} C[b][e]*(NEXP/(SEQ*TK)) * (Sm[b][e]/SEQ)
        float aux = 0.01f * accv * ((float)NEXP / ((float)SEQ * (float)TK))
                    / (float)SEQ / (float)NB;
        out[(size_t)NTOK * TK * 2] = aux;
    }
}

extern "C" void kernel_launch(void* const* d_in, const int* in_sizes, int n_in,
                              void* d_out, int out_size, void* d_ws, size_t ws_size,
                              hipStream_t stream)
{
    const float* hidden = (const float*)d_in[0];
    const float* weight = (const float*)d_in[1];
    float* out = (float*)d_out;
    float* ws  = (float*)d_ws;

    hipMemsetAsync(d_ws, 0, 2 * NB * NEXP * sizeof(float), stream);
    moe_main<<<NTOK / TB, NTHR, 0, stream>>>(hidden, weight, out, ws);
    moe_finalize<<<1, 64, 0, stream>>>(ws, out);
}